// Round 1
// baseline (884.177 us; speedup 1.0000x reference)
//
#include <hip/hip_runtime.h>

#define RESO 128
#define SH_C 27

__global__ __launch_bounds__(256) void sample_grid_kernel(
    const float* __restrict__ density,   // [CAP, 1]
    const float* __restrict__ sh,        // [CAP, 27]
    const int*   __restrict__ links,     // [128,128,128]
    const float* __restrict__ points,    // [N, 3]
    float* __restrict__ out_d,           // [N]
    float* __restrict__ out_sh,          // [N, 27]
    int n)
{
    int i = blockIdx.x * blockDim.x + threadIdx.x;
    if (i >= n) return;

    float px = points[(size_t)i * 3 + 0];
    float py = points[(size_t)i * 3 + 1];
    float pz = points[(size_t)i * 3 + 2];

    // clip to [0, reso-1]
    px = fminf(fmaxf(px, 0.0f), (float)(RESO - 1));
    py = fminf(fmaxf(py, 0.0f), (float)(RESO - 1));
    pz = fminf(fmaxf(pz, 0.0f), (float)(RESO - 1));

    int lx = (int)floorf(px); lx = min(max(lx, 0), RESO - 2);
    int ly = (int)floorf(py); ly = min(max(ly, 0), RESO - 2);
    int lz = (int)floorf(pz); lz = min(max(lz, 0), RESO - 2);

    float wx = px - (float)lx;
    float wy = py - (float)ly;
    float wz = pz - (float)lz;

    float accd = 0.0f;
    float accs[SH_C];
    #pragma unroll
    for (int c = 0; c < SH_C; ++c) accs[c] = 0.0f;

    const int base = lx * (RESO * RESO) + ly * RESO + lz;

    #pragma unroll
    for (int k = 0; k < 8; ++k) {
        const int dx = (k >> 2) & 1;
        const int dy = (k >> 1) & 1;
        const int dz = k & 1;
        const int idx = links[base + dx * (RESO * RESO) + dy * RESO + dz];
        if (idx >= 0) {
            const float fx = dx ? wx : 1.0f - wx;
            const float fy = dy ? wy : 1.0f - wy;
            const float fz = dz ? wz : 1.0f - wz;
            const float wt = fx * fy * fz;
            accd = fmaf(wt, density[idx], accd);
            const float* __restrict__ row = sh + (size_t)idx * SH_C;
            #pragma unroll
            for (int c = 0; c < SH_C; ++c)
                accs[c] = fmaf(wt, row[c], accs[c]);
        }
    }

    out_d[i] = accd;
    float* __restrict__ o = out_sh + (size_t)i * SH_C;
    #pragma unroll
    for (int c = 0; c < SH_C; ++c) o[c] = accs[c];
}

extern "C" void kernel_launch(void* const* d_in, const int* in_sizes, int n_in,
                              void* d_out, int out_size, void* d_ws, size_t ws_size,
                              hipStream_t stream) {
    const float* density = (const float*)d_in[0];  // [CAP,1]
    const float* sh      = (const float*)d_in[1];  // [CAP,27]
    const int*   links   = (const int*)d_in[2];    // [128,128,128]
    const float* points  = (const float*)d_in[3];  // [N,3]

    const int n = in_sizes[3] / 3;                 // N_PTS

    float* out_d  = (float*)d_out;                 // first N floats
    float* out_sh = out_d + n;                     // then N*27 floats

    const int block = 256;
    const int grid  = (n + block - 1) / block;
    sample_grid_kernel<<<grid, block, 0, stream>>>(density, sh, links, points,
                                                   out_d, out_sh, n);
}

// Round 2
// 732.975 us; speedup vs baseline: 1.2063x; 1.2063x over previous
//
#include <hip/hip_runtime.h>

#define RESO 128
#define SH_C 27
#define NCELLS (32*32*32)   // cell = 4^3 voxels

// ---------------- helpers ----------------
__device__ __forceinline__ void point_to_voxel(float px, float py, float pz,
                                               int& lx, int& ly, int& lz,
                                               float& cx, float& cy, float& cz) {
    cx = fminf(fmaxf(px, 0.0f), (float)(RESO - 1));
    cy = fminf(fmaxf(py, 0.0f), (float)(RESO - 1));
    cz = fminf(fmaxf(pz, 0.0f), (float)(RESO - 1));
    lx = min(max((int)floorf(cx), 0), RESO - 2);
    ly = min(max((int)floorf(cy), 0), RESO - 2);
    lz = min(max((int)floorf(cz), 0), RESO - 2);
}

__device__ __forceinline__ int cell_of(int lx, int ly, int lz) {
    return ((lx >> 2) << 10) | ((ly >> 2) << 5) | (lz >> 2);
}

// ---------------- sort passes ----------------
__global__ __launch_bounds__(256) void hist_kernel(
    const float* __restrict__ pts, int* __restrict__ hist, int n)
{
    int i = blockIdx.x * blockDim.x + threadIdx.x;
    if (i >= n) return;
    int lx, ly, lz; float cx, cy, cz;
    point_to_voxel(pts[3*(size_t)i], pts[3*(size_t)i+1], pts[3*(size_t)i+2],
                   lx, ly, lz, cx, cy, cz);
    atomicAdd(&hist[cell_of(lx, ly, lz)], 1);
}

// exclusive scan of NCELLS ints in place, single block of 1024 threads
__global__ __launch_bounds__(1024) void scan_kernel(int* __restrict__ hist)
{
    __shared__ int sums[1024];
    const int t = threadIdx.x;
    const int base = t * (NCELLS / 1024);
    int local[NCELLS / 1024];
    int s = 0;
    #pragma unroll
    for (int k = 0; k < NCELLS / 1024; ++k) { local[k] = s; s += hist[base + k]; }
    sums[t] = s;
    __syncthreads();
    for (int off = 1; off < 1024; off <<= 1) {
        int v = (t >= off) ? sums[t - off] : 0;
        __syncthreads();
        sums[t] += v;
        __syncthreads();
    }
    const int prev = (t == 0) ? 0 : sums[t - 1];
    #pragma unroll
    for (int k = 0; k < NCELLS / 1024; ++k) hist[base + k] = prev + local[k];
}

__global__ __launch_bounds__(256) void scatter_kernel(
    const float* __restrict__ pts, int* __restrict__ cursor,
    float4* __restrict__ spts, int n)
{
    int i = blockIdx.x * blockDim.x + threadIdx.x;
    if (i >= n) return;
    float px = pts[3*(size_t)i], py = pts[3*(size_t)i+1], pz = pts[3*(size_t)i+2];
    int lx, ly, lz; float cx, cy, cz;
    point_to_voxel(px, py, pz, lx, ly, lz, cx, cy, cz);
    int slot = atomicAdd(&cursor[cell_of(lx, ly, lz)], 1);
    float4 v; v.x = px; v.y = py; v.z = pz; v.w = __int_as_float(i);
    spts[slot] = v;
}

// ---------------- main gather ----------------
__global__ __launch_bounds__(256) void sample_sorted_kernel(
    const float* __restrict__ density,   // [CAP, 1]
    const float* __restrict__ sh,        // [CAP, 27]
    const int*   __restrict__ links,     // [128,128,128]
    const float4* __restrict__ spts,     // sorted points (x,y,z,orig-idx)
    float* __restrict__ out_d,           // [N]
    float* __restrict__ out_sh,          // [N, 27]
    int n)
{
    int t = blockIdx.x * blockDim.x + threadIdx.x;
    if (t >= n) return;

    float4 pv = spts[t];
    const int orig = __float_as_int(pv.w);

    int lx, ly, lz; float cx, cy, cz;
    point_to_voxel(pv.x, pv.y, pv.z, lx, ly, lz, cx, cy, cz);

    const float wx = cx - (float)lx;
    const float wy = cy - (float)ly;
    const float wz = cz - (float)lz;

    float accd = 0.0f;
    float accs[SH_C];
    #pragma unroll
    for (int c = 0; c < SH_C; ++c) accs[c] = 0.0f;

    const int base = lx * (RESO * RESO) + ly * RESO + lz;

    #pragma unroll
    for (int k = 0; k < 8; ++k) {
        const int dx = (k >> 2) & 1;
        const int dy = (k >> 1) & 1;
        const int dz = k & 1;
        const int idx = links[base + dx * (RESO * RESO) + dy * RESO + dz];
        if (idx >= 0) {
            const float fx = dx ? wx : 1.0f - wx;
            const float fy = dy ? wy : 1.0f - wy;
            const float fz = dz ? wz : 1.0f - wz;
            const float wt = fx * fy * fz;
            accd = fmaf(wt, density[idx], accd);
            const float* __restrict__ row = sh + (size_t)idx * SH_C;
            #pragma unroll
            for (int c = 0; c < SH_C; ++c)
                accs[c] = fmaf(wt, row[c], accs[c]);
        }
    }

    out_d[orig] = accd;
    float* __restrict__ o = out_sh + (size_t)orig * SH_C;
    #pragma unroll
    for (int c = 0; c < SH_C; ++c) o[c] = accs[c];
}

// fallback (round-1 kernel) if ws too small
__global__ __launch_bounds__(256) void sample_direct_kernel(
    const float* __restrict__ density, const float* __restrict__ sh,
    const int* __restrict__ links, const float* __restrict__ points,
    float* __restrict__ out_d, float* __restrict__ out_sh, int n)
{
    int i = blockIdx.x * blockDim.x + threadIdx.x;
    if (i >= n) return;
    int lx, ly, lz; float cx, cy, cz;
    point_to_voxel(points[3*(size_t)i], points[3*(size_t)i+1], points[3*(size_t)i+2],
                   lx, ly, lz, cx, cy, cz);
    const float wx = cx - (float)lx, wy = cy - (float)ly, wz = cz - (float)lz;
    float accd = 0.0f, accs[SH_C];
    #pragma unroll
    for (int c = 0; c < SH_C; ++c) accs[c] = 0.0f;
    const int base = lx * (RESO * RESO) + ly * RESO + lz;
    #pragma unroll
    for (int k = 0; k < 8; ++k) {
        const int dx = (k >> 2) & 1, dy = (k >> 1) & 1, dz = k & 1;
        const int idx = links[base + dx * (RESO * RESO) + dy * RESO + dz];
        if (idx >= 0) {
            const float wt = (dx ? wx : 1.0f - wx) * (dy ? wy : 1.0f - wy) * (dz ? wz : 1.0f - wz);
            accd = fmaf(wt, density[idx], accd);
            const float* row = sh + (size_t)idx * SH_C;
            #pragma unroll
            for (int c = 0; c < SH_C; ++c) accs[c] = fmaf(wt, row[c], accs[c]);
        }
    }
    out_d[i] = accd;
    float* o = out_sh + (size_t)i * SH_C;
    #pragma unroll
    for (int c = 0; c < SH_C; ++c) o[c] = accs[c];
}

extern "C" void kernel_launch(void* const* d_in, const int* in_sizes, int n_in,
                              void* d_out, int out_size, void* d_ws, size_t ws_size,
                              hipStream_t stream) {
    const float* density = (const float*)d_in[0];
    const float* sh      = (const float*)d_in[1];
    const int*   links   = (const int*)d_in[2];
    const float* points  = (const float*)d_in[3];

    const int n = in_sizes[3] / 3;

    float* out_d  = (float*)d_out;
    float* out_sh = out_d + n;

    const int block = 256;
    const int grid  = (n + block - 1) / block;

    // ws layout: hist[NCELLS] ints | pad | sorted float4[n]
    const size_t hist_bytes = (size_t)NCELLS * sizeof(int);
    const size_t spts_off   = (hist_bytes + 255) & ~(size_t)255;
    const size_t need       = spts_off + (size_t)n * sizeof(float4);

    if (ws_size >= need) {
        int*    hist = (int*)d_ws;
        float4* spts = (float4*)((char*)d_ws + spts_off);

        hipMemsetAsync(hist, 0, hist_bytes, stream);
        hist_kernel<<<grid, block, 0, stream>>>(points, hist, n);
        scan_kernel<<<1, 1024, 0, stream>>>(hist);
        scatter_kernel<<<grid, block, 0, stream>>>(points, hist, spts, n);
        sample_sorted_kernel<<<grid, block, 0, stream>>>(density, sh, links, spts,
                                                         out_d, out_sh, n);
    } else {
        sample_direct_kernel<<<grid, block, 0, stream>>>(density, sh, links, points,
                                                         out_d, out_sh, n);
    }
}

// Round 3
// 563.620 us; speedup vs baseline: 1.5687x; 1.3005x over previous
//
#include <hip/hip_runtime.h>
#include <hip/hip_fp16.h>

#define RESO 128
#define SH_C 27
#define NCELLS (32*32*32)   // cell = 4^3 voxels

// ---------------- helpers ----------------
__device__ __forceinline__ void point_to_voxel(float px, float py, float pz,
                                               int& lx, int& ly, int& lz,
                                               float& cx, float& cy, float& cz) {
    cx = fminf(fmaxf(px, 0.0f), (float)(RESO - 1));
    cy = fminf(fmaxf(py, 0.0f), (float)(RESO - 1));
    cz = fminf(fmaxf(pz, 0.0f), (float)(RESO - 1));
    lx = min(max((int)floorf(cx), 0), RESO - 2);
    ly = min(max((int)floorf(cy), 0), RESO - 2);
    lz = min(max((int)floorf(cz), 0), RESO - 2);
}

__device__ __forceinline__ int cell_of(int lx, int ly, int lz) {
    return ((lx >> 2) << 10) | ((ly >> 2) << 5) | (lz >> 2);
}

// ---------------- pack density+sh into one 64B fp16 row ----------------
// layout: half[0] = density, half[1..27] = sh[0..26], half[28..31] = 0
__global__ __launch_bounds__(256) void pack_kernel(
    const float* __restrict__ density, const float* __restrict__ sh,
    uint4* __restrict__ packed4, int cap)
{
    int r = blockIdx.x * blockDim.x + threadIdx.x;
    if (r >= cap) return;
    union { uint4 q[4]; __half h[32]; } pk;
    pk.h[0] = __float2half(density[r]);
    const float* __restrict__ row = sh + (size_t)r * SH_C;
    #pragma unroll
    for (int c = 0; c < SH_C; ++c) pk.h[1 + c] = __float2half(row[c]);
    #pragma unroll
    for (int c = 28; c < 32; ++c) pk.h[c] = __float2half(0.0f);
    uint4* __restrict__ dst = packed4 + (size_t)r * 4;
    dst[0] = pk.q[0]; dst[1] = pk.q[1]; dst[2] = pk.q[2]; dst[3] = pk.q[3];
}

// ---------------- sort passes ----------------
__global__ __launch_bounds__(256) void hist_kernel(
    const float* __restrict__ pts, int* __restrict__ hist, int n)
{
    int i = blockIdx.x * blockDim.x + threadIdx.x;
    if (i >= n) return;
    int lx, ly, lz; float cx, cy, cz;
    point_to_voxel(pts[3*(size_t)i], pts[3*(size_t)i+1], pts[3*(size_t)i+2],
                   lx, ly, lz, cx, cy, cz);
    atomicAdd(&hist[cell_of(lx, ly, lz)], 1);
}

// exclusive scan of NCELLS ints in place, single block of 1024 threads
__global__ __launch_bounds__(1024) void scan_kernel(int* __restrict__ hist)
{
    __shared__ int sums[1024];
    const int t = threadIdx.x;
    const int base = t * (NCELLS / 1024);
    int local[NCELLS / 1024];
    int s = 0;
    #pragma unroll
    for (int k = 0; k < NCELLS / 1024; ++k) { local[k] = s; s += hist[base + k]; }
    sums[t] = s;
    __syncthreads();
    for (int off = 1; off < 1024; off <<= 1) {
        int v = (t >= off) ? sums[t - off] : 0;
        __syncthreads();
        sums[t] += v;
        __syncthreads();
    }
    const int prev = (t == 0) ? 0 : sums[t - 1];
    #pragma unroll
    for (int k = 0; k < NCELLS / 1024; ++k) hist[base + k] = prev + local[k];
}

__global__ __launch_bounds__(256) void scatter_kernel(
    const float* __restrict__ pts, int* __restrict__ cursor,
    float4* __restrict__ spts, int n)
{
    int i = blockIdx.x * blockDim.x + threadIdx.x;
    if (i >= n) return;
    float px = pts[3*(size_t)i], py = pts[3*(size_t)i+1], pz = pts[3*(size_t)i+2];
    int lx, ly, lz; float cx, cy, cz;
    point_to_voxel(px, py, pz, lx, ly, lz, cx, cy, cz);
    int slot = atomicAdd(&cursor[cell_of(lx, ly, lz)], 1);
    float4 v; v.x = px; v.y = py; v.z = pz; v.w = __int_as_float(i);
    spts[slot] = v;
}

// ---------------- main gather (packed fp16 rows) ----------------
__global__ __launch_bounds__(256) void sample_sorted_kernel(
    const uint4* __restrict__ packed4,   // [CAP, 4] uint4 = 64B row
    const int*   __restrict__ links,     // [128,128,128]
    const float4* __restrict__ spts,     // sorted points (x,y,z,orig-idx)
    float* __restrict__ out_d,           // [N]
    float* __restrict__ out_sh,          // [N, 27]
    int n)
{
    int t = blockIdx.x * blockDim.x + threadIdx.x;
    if (t >= n) return;

    float4 pv = spts[t];
    const int orig = __float_as_int(pv.w);

    int lx, ly, lz; float cx, cy, cz;
    point_to_voxel(pv.x, pv.y, pv.z, lx, ly, lz, cx, cy, cz);

    const float wx = cx - (float)lx;
    const float wy = cy - (float)ly;
    const float wz = cz - (float)lz;

    float acc[28];
    #pragma unroll
    for (int c = 0; c < 28; ++c) acc[c] = 0.0f;

    const int base = lx * (RESO * RESO) + ly * RESO + lz;

    #pragma unroll
    for (int k = 0; k < 8; ++k) {
        const int dx = (k >> 2) & 1;
        const int dy = (k >> 1) & 1;
        const int dz = k & 1;
        const int idx = links[base + dx * (RESO * RESO) + dy * RESO + dz];
        if (idx >= 0) {
            const float fx = dx ? wx : 1.0f - wx;
            const float fy = dy ? wy : 1.0f - wy;
            const float fz = dz ? wz : 1.0f - wz;
            const float wt = fx * fy * fz;
            union { uint4 q[4]; __half2 h2[16]; } pk;
            const uint4* __restrict__ pr = packed4 + (size_t)idx * 4;
            pk.q[0] = pr[0]; pk.q[1] = pr[1]; pk.q[2] = pr[2]; pk.q[3] = pr[3];
            #pragma unroll
            for (int j = 0; j < 14; ++j) {          // 28 halves
                float2 f = __half22float2(pk.h2[j]);
                acc[2*j]     = fmaf(wt, f.x, acc[2*j]);
                acc[2*j + 1] = fmaf(wt, f.y, acc[2*j + 1]);
            }
        }
    }

    out_d[orig] = acc[0];
    float* __restrict__ o = out_sh + (size_t)orig * SH_C;
    #pragma unroll
    for (int c = 0; c < SH_C; ++c) o[c] = acc[1 + c];
}

// fallback (round-1 kernel) if ws too small
__global__ __launch_bounds__(256) void sample_direct_kernel(
    const float* __restrict__ density, const float* __restrict__ sh,
    const int* __restrict__ links, const float* __restrict__ points,
    float* __restrict__ out_d, float* __restrict__ out_sh, int n)
{
    int i = blockIdx.x * blockDim.x + threadIdx.x;
    if (i >= n) return;
    int lx, ly, lz; float cx, cy, cz;
    point_to_voxel(points[3*(size_t)i], points[3*(size_t)i+1], points[3*(size_t)i+2],
                   lx, ly, lz, cx, cy, cz);
    const float wx = cx - (float)lx, wy = cy - (float)ly, wz = cz - (float)lz;
    float accd = 0.0f, accs[SH_C];
    #pragma unroll
    for (int c = 0; c < SH_C; ++c) accs[c] = 0.0f;
    const int base = lx * (RESO * RESO) + ly * RESO + lz;
    #pragma unroll
    for (int k = 0; k < 8; ++k) {
        const int dx = (k >> 2) & 1, dy = (k >> 1) & 1, dz = k & 1;
        const int idx = links[base + dx * (RESO * RESO) + dy * RESO + dz];
        if (idx >= 0) {
            const float wt = (dx ? wx : 1.0f - wx) * (dy ? wy : 1.0f - wy) * (dz ? wz : 1.0f - wz);
            accd = fmaf(wt, density[idx], accd);
            const float* row = sh + (size_t)idx * SH_C;
            #pragma unroll
            for (int c = 0; c < SH_C; ++c) accs[c] = fmaf(wt, row[c], accs[c]);
        }
    }
    out_d[i] = accd;
    float* o = out_sh + (size_t)i * SH_C;
    #pragma unroll
    for (int c = 0; c < SH_C; ++c) o[c] = accs[c];
}

extern "C" void kernel_launch(void* const* d_in, const int* in_sizes, int n_in,
                              void* d_out, int out_size, void* d_ws, size_t ws_size,
                              hipStream_t stream) {
    const float* density = (const float*)d_in[0];
    const float* sh      = (const float*)d_in[1];
    const int*   links   = (const int*)d_in[2];
    const float* points  = (const float*)d_in[3];

    const int cap = in_sizes[0];
    const int n   = in_sizes[3] / 3;

    float* out_d  = (float*)d_out;
    float* out_sh = out_d + n;

    const int block = 256;
    const int grid  = (n + block - 1) / block;
    const int gridc = (cap + block - 1) / block;

    // ws layout: hist[NCELLS] ints | spts float4[n] | packed uint4[cap*4]
    const size_t hist_bytes = (size_t)NCELLS * sizeof(int);
    const size_t spts_off   = (hist_bytes + 255) & ~(size_t)255;
    const size_t pack_off   = (spts_off + (size_t)n * sizeof(float4) + 255) & ~(size_t)255;
    const size_t need       = pack_off + (size_t)cap * 64;

    if (ws_size >= need) {
        int*    hist    = (int*)d_ws;
        float4* spts    = (float4*)((char*)d_ws + spts_off);
        uint4*  packed4 = (uint4*)((char*)d_ws + pack_off);

        hipMemsetAsync(hist, 0, hist_bytes, stream);
        hist_kernel<<<grid, block, 0, stream>>>(points, hist, n);
        pack_kernel<<<gridc, block, 0, stream>>>(density, sh, packed4, cap);
        scan_kernel<<<1, 1024, 0, stream>>>(hist);
        scatter_kernel<<<grid, block, 0, stream>>>(points, hist, spts, n);
        sample_sorted_kernel<<<grid, block, 0, stream>>>(packed4, links, spts,
                                                         out_d, out_sh, n);
    } else {
        sample_direct_kernel<<<grid, block, 0, stream>>>(density, sh, links, points,
                                                         out_d, out_sh, n);
    }
}